// Round 7
// baseline (124.212 us; speedup 1.0000x reference)
//
#include <hip/hip_runtime.h>
#include <math.h>

// Highpass biquad: FIR(b0,b1,b2) + IIR(a1,a2) recurrence, clamp [-1,1].
// R15 = R13 base (best: 114.4us) + DIRECT REGISTER STORES.
// R14 post-mortem: reg-staging regressed (46us, VGPR=80 - compiler
// refused to hold a[16]+bb[16], broke the prologue into serialized
// load->wait->ds_write groups at full HBM latency). DMA staging stands.
// Real traffic (first direct counters): FETCH 33MB (input half-L3-
// resident) + WRITE 66MB = 100MB -> floor ~16us; R13 ~29us = 3.4 TB/s.
// R13's residual flaw: bursty phase-locked issue + 5x LDS traffic per
// byte (in: DMA-write+warmup-read+main-read; out: main-WRITE + store-
// phase READ + global). Fix: store outputs DIRECTLY from the recurrence
// registers. Lane t's 64 samples are contiguous 256B -> per-lane f4
// CACHED stores (write-back L2 merges 16B sectors into full lines
// across the 16-instr loop; NT would couple the scatter to DRAM).
// Wins: (1) -32 LDS instr/segment (no main LDS writeback, no store
// phase), (2) stores trickle out DURING compute (continuous write
// issue instead of end-of-segment burst), (3) segment ends right after
// main -> next vmcnt wait + prefetch ~400cyc earlier, (4) in-place LDS
// hazard gone (buffer read-only after staging).
// vmcnt(16) stays correct with interleaved stores: vmcnt retirement is
// IN-ORDER (m135), and the 16 stores of seg s are the newest VMEM ops
// at seg s+1's wait -> outstanding<=16 ==> all older ops (the prefetch
// loads) retired.
// Kept from R13 (proven): 2-deep ping-pong pipeline (SPB=4, prologue
// DMAs seg0+seg1, iter s prefetches s+1 under s's compute); bijective
// XCD swizzle (1024%8==0: XCD x owns a contiguous ~8MB slice);
// XOR-swizzled LDS slot(r,p')=16r|(p'^(r&15)) - bank-quad balanced in
// every phase, all ds traffic b128; global_load_lds width=16 with
// linear LDS dest + inverse-swizzled global source; segment chaining
// via lane-63 __shfl (exact state + exact FIR ICs, HW-verified);
// s==0 head state via masked prologue register loads (oldest in queue,
// retired by first vmcnt(16)). No barriers (1-wave blocks).
// 2x16KB LDS -> 4 blocks/CU resident (1024 blocks = 1 generation).
// Coefficients in float (HW v_sin/v_cos): err ~1e-7 << absmax 3.9e-3,
// threshold 1.06e-2. Warmup length 64: boundary err 0.904^64 ~ 1.6e-3.

constexpr int T_LEN  = 131072;
constexpr int L      = 64;               // samples per chunk (= per thread)
constexpr int CPB    = 64;               // chunks per segment = 1 wave
constexpr int SEG    = CPB * L;          // 4096 floats per segment
constexpr int SPB    = 4;                // segments per block (pipelined)
constexpr int GRP_PER_SEQ = T_LEN / (SEG * SPB); // 8
constexpr int NSEQ   = 64 * 2;           // 128 sequences
constexpr int NBLOCKS = NSEQ * GRP_PER_SEQ;      // 1024 (divisible by 8)

typedef float fx4 __attribute__((ext_vector_type(4)));

#define AS1(p) ((const __attribute__((address_space(1))) void*)(p))
#define AS3(p) ((__attribute__((address_space(3))) void*)(p))

__global__ __launch_bounds__(64) void hp_kernel(
    const float* __restrict__ x,
    const float* __restrict__ pfreq,
    const float* __restrict__ pq,
    float* __restrict__ out)
{
    __shared__ fx4 lds4[2][CPB * 16];    // 2 x 16384 B ping-pong

    // --- coefficients (float; HW trig) ---
    float freq = fminf(fmaxf(pfreq[0], 100.0f), 44100.0f * 0.5f - 1.0f);
    float q    = fminf(fmaxf(pq[0], 0.1f), 10.0f);
    float w0   = 2.0f * (float)M_PI * freq / 44100.0f;
    float cw   = cosf(w0);
    float alpha = sinf(w0) / (2.0f * q);
    float ia0  = 1.0f / (1.0f + alpha);
    const float b0 = (1.0f + cw) * 0.5f * ia0;
    const float b1 = -(1.0f + cw) * ia0;
    const float b2 = b0;
    const float a1 = -2.0f * cw * ia0;
    const float a2 = (1.0f - alpha) * ia0;

    // bijective XCD swizzle: XCD x owns orig-blocks [x*128,(x+1)*128) =
    // a contiguous ~8MB slice of input+output.
    const int borig = blockIdx.x;
    const int b     = ((borig & 7) << 7) | (borig >> 3);

    const int seq = b >> 3;              // / GRP_PER_SEQ
    const int S0  = (b & (GRP_PER_SEQ - 1)) * (SEG * SPB);
    const float* __restrict__ xs = x   + (size_t)seq * T_LEN;
    float*       __restrict__ os = out + (size_t)seq * T_LEN;
    const int tid = threadIdx.x;

    // --- prologue global loads with REGISTER dests, issued first (oldest
    // in the vmcnt queue, retired by the first vmcnt(16)) ---
    // s==0 FIR ICs for tid<2 (tail of chunk cgm-2, not staged):
    float hp1 = 0.f, hp2 = 0.f;
    if (S0 > 0 && tid < 2) {
        const float* w = xs + S0 + (tid - 1) * L;
        hp1 = w[-1]; hp2 = w[-2];
    }
    // s==0 warmup head for tid==0 (previous group's last chunk):
    fx4 h[16];
    if (S0 > 0 && tid == 0) {
        const fx4* gw = (const fx4*)(xs + S0 - L);
#pragma unroll
        for (int k = 0; k < 16; ++k) h[k] = gw[k];
    }

    // --- prologue DMA: seg0 -> buf0, seg1 -> buf1 (inverse-swizzled src) ---
#pragma unroll
    for (int k = 0; k < 16; ++k) {
        int s4 = tid + (k << 6);
        int r  = s4 >> 4;
        int g  = (r << 4) | ((s4 & 15) ^ (r & 15));
        __builtin_amdgcn_global_load_lds(AS1(xs + S0 + (g << 2)),
                                         AS3(&lds4[0][k << 6]), 16, 0, 0);
    }
#pragma unroll
    for (int k = 0; k < 16; ++k) {
        int s4 = tid + (k << 6);
        int r  = s4 >> 4;
        int g  = (r << 4) | ((s4 & 15) ^ (r & 15));
        __builtin_amdgcn_global_load_lds(AS1(xs + S0 + SEG + (g << 2)),
                                         AS3(&lds4[1][k << 6]), 16, 0, 0);
    }

    // chained exact state from lane 63 (valid for s>0)
    float ny1 = 0.f, ny2 = 0.f, np1 = 0.f, np2 = 0.f;

    // y = (xf - a2*y2) - a1*y1 => critical path y1->y is one FMA (~4cyc)
#define STEP(xv) { \
        float xf_ = fmaf(b2, p2, fmaf(b1, p1, b0 * (xv))); \
        float yv  = fmaf(-a1, y1, fmaf(-a2, y2, xf_)); \
        p2 = p1; p1 = (xv); y2 = y1; y1 = yv; }

#pragma unroll 1
    for (int s = 0; s < SPB; ++s) {
        const int S = S0 + s * SEG;
        fx4* buf = lds4[s & 1];

        // Counted wait: in-order retirement => outstanding<=16 means all
        // ops older than the newest 16 (= prior segment's stores) have
        // retired, incl. this segment's DMA loads. lgkmcnt(0): this
        // buffer's last ds_reads (seg s-2) drained -> free to DMA into
        // the other buffer below.
        asm volatile("s_waitcnt vmcnt(16) lgkmcnt(0)" ::: "memory");
        __builtin_amdgcn_sched_barrier(0);

        // prefetch seg s+1 into the other buffer (flies under compute)
        if (s >= 1 && s + 1 < SPB) {
            fx4* nb = lds4[(s + 1) & 1];
            const float* gseg = xs + S + SEG;
#pragma unroll
            for (int k = 0; k < 16; ++k) {
                int s4 = tid + (k << 6);
                int r  = s4 >> 4;
                int g  = (r << 4) | ((s4 & 15) ^ (r & 15));
                __builtin_amdgcn_global_load_lds(AS1(gseg + (g << 2)),
                                                 AS3(&nb[k << 6]), 16, 0, 0);
            }
        }

        float y1, y2, p1, p2;

        // --- warmup: thread t converges state over row t-1 ---
        if (s == 0) {
            y1 = 0.f; y2 = 0.f; p1 = 0.f; p2 = 0.f;
            const int cgm = (S0 >> 6) + tid;    // global main-chunk index
            if (cgm >= 1) {
                if (cgm >= 2) {
                    if (tid >= 2) {             // tail of chunk cgm-2 in LDS
                        int rr = tid - 2;
                        const float* pr = (const float*)
                            (buf + ((rr << 4) | (15 ^ (rr & 15))));
                        p2 = pr[2]; p1 = pr[3];
                    } else { p1 = hp1; p2 = hp2; }
                }                               // cgm==1: zero ICs (exact)
                const fx4* rp = buf + (((tid - 1) & 63) << 4);
                const int  xr = (tid - 1) & 15;
#pragma unroll
                for (int j4 = 0; j4 < 16; ++j4) {
                    fx4 v = (tid == 0) ? h[j4] : rp[j4 ^ xr];
                    STEP(v.x); STEP(v.y); STEP(v.z); STEP(v.w);
                }
            }
            // cgm==0: exact zero ICs (matches reference padding)
        } else {
            if (tid == 0) {                     // exact chained state
                y1 = ny1; y2 = ny2; p1 = np1; p2 = np2;
            } else {
                y1 = 0.f; y2 = 0.f;
                if (tid >= 2) {
                    int rr = tid - 2;
                    const float* pr = (const float*)
                        (buf + ((rr << 4) | (15 ^ (rr & 15))));
                    p2 = pr[2]; p1 = pr[3];
                } else { p1 = np1; p2 = np2; }  // tid==1: exact via shfl
                const fx4* rp = buf + ((tid - 1) << 4);
                const int  xr = (tid - 1) & 15;
#pragma unroll
                for (int j4 = 0; j4 < 16; ++j4) {
                    fx4 v = rp[j4 ^ xr];
                    STEP(v.x); STEP(v.y); STEP(v.z); STEP(v.w);
                }
            }
        }

        // --- main over row tid with DIRECT per-lane stores: lane t's
        // outputs = samples [t*64,(t+1)*64) = contiguous 256B. Cached
        // f4 stores trickle out during the STEP dep-chain (continuous
        // write issue); L2 write-back merges sectors into full lines.
        // Buffer is read-only now (no in-place writeback). ---
        {
            const fx4* mrow = buf + (tid << 4);
            const int  xm   = tid & 15;
            fx4* ob = (fx4*)(os + S) + (tid << 4);
#pragma unroll
            for (int j4 = 0; j4 < 16; ++j4) {
                fx4 v = mrow[j4 ^ xm];
                fx4 o;
                STEP(v.x); o.x = fminf(fmaxf(y1, -1.f), 1.f);
                STEP(v.y); o.y = fminf(fmaxf(y1, -1.f), 1.f);
                STEP(v.z); o.z = fminf(fmaxf(y1, -1.f), 1.f);
                STEP(v.w); o.w = fminf(fmaxf(y1, -1.f), 1.f);
                ob[j4] = o;
            }
        }

        // chain lane 63's exact end-state to the next segment (unclamped
        // y's: the IIR recurrence runs on unclamped outputs, as in ref)
        ny1 = __shfl(y1, 63); ny2 = __shfl(y2, 63);
        np1 = __shfl(p1, 63); np2 = __shfl(p2, 63);
    }
#undef STEP
}

extern "C" void kernel_launch(void* const* d_in, const int* in_sizes, int n_in,
                              void* d_out, int out_size, void* d_ws, size_t ws_size,
                              hipStream_t stream) {
    const float* x  = (const float*)d_in[0];
    // d_in[1] = t, unused by the reference computation
    const float* ff = (const float*)d_in[2];
    const float* fq = (const float*)d_in[3];
    float* out = (float*)d_out;
    hp_kernel<<<NBLOCKS, CPB, 0, stream>>>(x, ff, fq, out);
}

// Round 9
// 114.115 us; speedup vs baseline: 1.0885x; 1.0885x over previous
//
#include <hip/hip_runtime.h>
#include <math.h>

// Highpass biquad: FIR(b0,b1,b2) + IIR(a1,a2) recurrence, clamp [-1,1].
// R17 = R16 + one-line correctness fix. R16 post-mortem: absmax 9.6e-2
// from ONE path - at S0==0, lane 1's second warmup loop took the tid<2
// register-head path but hh is zero-init when S0==0, so lane 1 warmed
// over ZEROS instead of the real (staged) row 0 -> its main row
// (samples 32..63) started from zero state. Fix: gate the register-head
// path with S0>0; at S0==0 lane 1 falls through to the staged LDS row
// (exact: row -1 = zeros via hh in loop 1, row 0 = real data via LDS in
// loop 2, ICs = zeros = reference padding). All other paths re-audited:
// lane0@S0==0 exact (cg guard), lane2 exact, lanes>=3 = 64-sample
// truncation (1.6e-3, same as all passing rounds), chains exact.
// Design (R16): R13 pipeline at DOUBLE residency (2 waves/SIMD).
// R13's flaw: 32KB ping-pong -> grid 1024 -> 1 wave/SIMD; a wave at its
// vmcnt/LDS stall leaves the SIMD idle. Halve the segment (L=32/lane,
// SEG=8KB), ping-pong 16KB -> grid 2048 -> 8 blocks/CU = 2 waves/SIMD,
// same in-flight bytes (64KB/CU). Counted wait now vmcnt(8).
// Accuracy: warmup window stays 64 samples = rows t-2,t-1. vs R13:
//  - lane 1's warmup head = prev seg's row 63 INPUT: captured to
//    hh[0..7] regs BEFORE main's in-place overwrite (in-order DS pipe).
//  - lane 1's exact FIR ICs = lane 62's post-main (p1,p2) via __shfl.
//  - lanes>=3 ICs from row t-3 tail (staged).
//  - s==0: lanes 0,1 load 64-sample head windows into hh (masked).
// Kept (proven): 2-deep ping-pong counted-vmcnt pipeline (never 0;
// in-order retirement => "<=8 left" == this seg's DMA landed);
// bijective XCD swizzle (2048%8==0); NT coalesced stores; XOR-swizzled
// LDS slot(r,p)=8r|(p^(r&7)) bank-quad balanced every phase, all ds
// b128; global_load_lds w=16 inverse-swizzled source; lane-63 __shfl
// chaining. No barriers (1-wave blocks). LDS 16KB; grid 2048 = 8/CU.
// Coefficients in float (HW v_sin/v_cos): err ~1e-7 << absmax 3.9e-3,
// threshold 1.06e-2.

constexpr int T_LEN  = 131072;
constexpr int L      = 32;               // samples per lane per segment
constexpr int CPB    = 64;               // lanes (= 1 wave)
constexpr int SEG    = CPB * L;          // 2048 floats per segment
constexpr int SPB    = 4;                // segments per block (pipelined)
constexpr int GRP    = SEG * SPB;        // 8192 samples per block
constexpr int GRP_PER_SEQ = T_LEN / GRP; // 16
constexpr int NSEQ   = 64 * 2;           // 128 sequences
constexpr int NBLOCKS = NSEQ * GRP_PER_SEQ;      // 2048 (divisible by 8)
constexpr int RPF    = L / 4;            // 8 f4 per row

typedef float fx4 __attribute__((ext_vector_type(4)));

#define AS1(p) ((const __attribute__((address_space(1))) void*)(p))
#define AS3(p) ((__attribute__((address_space(3))) void*)(p))
// row r (0..63), f4-col p (0..7) -> swizzled slot
#define SLOT(r, p) ((((r) & 63) << 3) | ((p) ^ ((r) & 7)))

__global__ __launch_bounds__(64) void hp_kernel(
    const float* __restrict__ x,
    const float* __restrict__ pfreq,
    const float* __restrict__ pq,
    float* __restrict__ out)
{
    __shared__ fx4 lds4[2][CPB * RPF];   // 2 x 8192 B ping-pong = 16 KB

    // --- coefficients (float; HW trig) ---
    float freq = fminf(fmaxf(pfreq[0], 100.0f), 44100.0f * 0.5f - 1.0f);
    float q    = fminf(fmaxf(pq[0], 0.1f), 10.0f);
    float w0   = 2.0f * (float)M_PI * freq / 44100.0f;
    float cw   = cosf(w0);
    float alpha = sinf(w0) / (2.0f * q);
    float ia0  = 1.0f / (1.0f + alpha);
    const float b0 = (1.0f + cw) * 0.5f * ia0;
    const float b1 = -(1.0f + cw) * ia0;
    const float b2 = b0;
    const float a1 = -2.0f * cw * ia0;
    const float a2 = (1.0f - alpha) * ia0;

    // bijective XCD swizzle: XCD x owns orig-blocks [x*256,(x+1)*256) =
    // a contiguous ~8MB slice of input+output.
    const int borig = blockIdx.x;
    const int b     = ((borig & 7) << 8) | (borig >> 3);

    const int seq = b >> 4;              // / GRP_PER_SEQ
    const int S0  = (b & (GRP_PER_SEQ - 1)) * GRP;
    const float* __restrict__ xs = x   + (size_t)seq * T_LEN;
    float*       __restrict__ os = out + (size_t)seq * T_LEN;
    const int tid = threadIdx.x;

    // --- prologue masked head loads (oldest in vmcnt queue) ---
    // ICs for lanes 0..2 at s==0: x[S0-64+32t-1], x[S0-64+32t-2]
    float hp1 = 0.f, hp2 = 0.f;
    if (S0 > 0 && tid < 3) {
        const float* wb = xs + S0 - 64 + (tid << 5);
        hp1 = wb[-1]; hp2 = wb[-2];
    }
    // 64-sample head windows for lanes 0,1 (rows t-2,t-1 of seg0):
    fx4 hh[16];
#pragma unroll
    for (int k = 0; k < 16; ++k) hh[k] = fx4{0.f, 0.f, 0.f, 0.f};
    if (S0 > 0 && tid < 2) {
        const fx4* gw = (const fx4*)(xs + S0 - 64 + (tid << 5));
#pragma unroll
        for (int k = 0; k < 16; ++k) hh[k] = gw[k];
    }

    // --- prologue DMA: seg0 -> buf0, seg1 -> buf1 (inverse-swizzled src) ---
#pragma unroll
    for (int k = 0; k < 8; ++k) {
        int s4 = (k << 6) + tid;             // dest slot (linear)
        int r  = s4 >> 3;
        int g  = (r << 3) | ((s4 & 7) ^ (r & 7));  // source f4 index
        __builtin_amdgcn_global_load_lds(AS1(xs + S0 + (g << 2)),
                                         AS3(&lds4[0][k << 6]), 16, 0, 0);
    }
#pragma unroll
    for (int k = 0; k < 8; ++k) {
        int s4 = (k << 6) + tid;
        int r  = s4 >> 3;
        int g  = (r << 3) | ((s4 & 7) ^ (r & 7));
        __builtin_amdgcn_global_load_lds(AS1(xs + S0 + SEG + (g << 2)),
                                         AS3(&lds4[1][k << 6]), 16, 0, 0);
    }

    // chained exact state (lane 63 -> lane 0; lane 62 -> lane 1 ICs)
    float ny1 = 0.f, ny2 = 0.f, np1 = 0.f, np2 = 0.f;
    float mp1 = 0.f, mp2 = 0.f;

    // y = (xf - a2*y2) - a1*y1 => critical path y1->y is one FMA (~4cyc)
#define STEP(xv) { \
        float xf_ = fmaf(b2, p2, fmaf(b1, p1, b0 * (xv))); \
        float yv  = fmaf(-a1, y1, fmaf(-a2, y2, xf_)); \
        p2 = p1; p1 = (xv); y2 = y1; y1 = yv; }
#define STEP4(v) { STEP((v).x); STEP((v).y); STEP((v).z); STEP((v).w); }

#pragma unroll 1
    for (int s = 0; s < SPB; ++s) {
        const int S = S0 + s * SEG;
        fx4* buf = lds4[s & 1];
        fx4* nb  = lds4[(s & 1) ^ 1];

        // Counted wait: in-order retirement => outstanding<=8 means all
        // older ops (this seg's DMA + any head loads) retired; the
        // newest 8 (prev stores / in-flight prefetch) stay in flight.
        // lgkmcnt(0): nb's store-phase ds_reads (seg s-1) drained.
        asm volatile("s_waitcnt vmcnt(8) lgkmcnt(0)" ::: "memory");
        __builtin_amdgcn_sched_barrier(0);

        // prefetch seg s+1 into nb (flies under this segment's compute)
        if (s >= 1 && s + 1 < SPB) {
            const float* gseg = xs + S + SEG;
#pragma unroll
            for (int k = 0; k < 8; ++k) {
                int s4 = (k << 6) + tid;
                int r  = s4 >> 3;
                int g  = (r << 3) | ((s4 & 7) ^ (r & 7));
                __builtin_amdgcn_global_load_lds(AS1(gseg + (g << 2)),
                                                 AS3(&nb[k << 6]), 16, 0, 0);
            }
        }

        float y1, y2, p1, p2;
        const int rm2 = (tid - 2) & 63, rm1 = (tid - 1) & 63;

        if (s == 0) {
            y1 = 0.f; y2 = 0.f; p1 = 0.f; p2 = 0.f;
            const int cg = (S0 >> 5) + tid;  // global chunk idx of main row
            if (cg >= 1) {                   // block0/lane0: exact zero ICs
                if (tid >= 3) {              // ICs = row t-3 tail (staged)
                    const float* pr = (const float*)(buf + SLOT(tid - 3, 7));
                    p2 = pr[2]; p1 = pr[3];
                } else { p1 = hp1; p2 = hp2; }
                // warmup rows t-2, t-1 (lanes<2: register head windows).
                // Loop 1: row t-2. S0==0, lane1: row -1 = zeros = hh ✓.
#pragma unroll
                for (int j = 0; j < 8; ++j) {
                    fx4 lv = buf[SLOT(rm2, j)];
                    fx4 v = (tid < 2) ? hh[j] : lv;
                    STEP4(v);
                }
                // Loop 2: row t-1. FIX: at S0==0 lane1's row t-1 = row 0
                // is REAL staged data -> use LDS, not zero-init hh.
#pragma unroll
                for (int j = 0; j < 8; ++j) {
                    fx4 lv = buf[SLOT(rm1, j)];
                    fx4 v = (tid < 2 && S0 > 0) ? hh[j + 8] : lv;
                    STEP4(v);
                }
            }
        } else {
            y1 = 0.f; y2 = 0.f;
            if (tid >= 3) {                  // ICs = row t-3 tail
                const float* pr = (const float*)(buf + SLOT(tid - 3, 7));
                p2 = pr[2]; p1 = pr[3];
            } else {                         // exact chained ICs via shfl
                p1 = (tid == 1) ? mp1 : np1;
                p2 = (tid == 1) ? mp2 : np2;
            }
            // warmup rows t-2, t-1; lane1 row t-2 = prev seg row 63 = hh
#pragma unroll
            for (int j = 0; j < 8; ++j) {
                fx4 lv = buf[SLOT(rm2, j)];
                fx4 v = (tid < 2) ? hh[j] : lv;  // lane0 garbage, replaced
                STEP4(v);
            }
#pragma unroll
            for (int j = 0; j < 8; ++j) {
                fx4 v = buf[SLOT(rm1, j)];       // lane1: row 0 (correct)
                STEP4(v);
            }
            if (tid == 0) {                  // exact chained state
                y1 = ny1; y2 = ny2; p1 = np1; p2 = np2;
            }
        }

        // capture NEXT iter's lane-1 head: row 63 INPUT, before main's
        // in-place overwrite destroys it (reads precede writes in wave
        // program order; in-order DS pipe).
        if (s + 1 < SPB && tid < 2) {
#pragma unroll
            for (int j = 0; j < 8; ++j) hh[j] = buf[SLOT(63, j)];
        }

        // --- main: in-place over row tid (safe: in-order single wave) ---
        {
            fx4* mrow = buf + (tid << 3);
            const int xm = tid & 7;
#pragma unroll
            for (int j = 0; j < 8; ++j) {
                int idx = j ^ xm;
                fx4 v = mrow[idx];
                fx4 o;
                STEP(v.x); o.x = fminf(fmaxf(y1, -1.f), 1.f);
                STEP(v.y); o.y = fminf(fmaxf(y1, -1.f), 1.f);
                STEP(v.z); o.z = fminf(fmaxf(y1, -1.f), 1.f);
                STEP(v.w); o.w = fminf(fmaxf(y1, -1.f), 1.f);
                mrow[idx] = o;
            }
        }

        // chain exact end-states (unclamped recurrence, as in reference):
        // lane63 -> next lane0 state + lane2 ICs; lane62 -> lane1 ICs.
        ny1 = __shfl(y1, 63); ny2 = __shfl(y2, 63);
        np1 = __shfl(p1, 63); np2 = __shfl(p2, 63);
        mp1 = __shfl(p1, 62); mp2 = __shfl(p2, 62);

        // --- coalesced NT store: swizzled slots -> contiguous f4 ---
        {
            fx4* ob = (fx4*)(os + S);
#pragma unroll
            for (int k = 0; k < 8; ++k) {
                int f = (k << 6) + tid;
                int r = f >> 3;
                fx4 v = buf[(r << 3) | ((f & 7) ^ (r & 7))];
                __builtin_nontemporal_store(v, &ob[f]);
            }
        }
    }
#undef STEP4
#undef STEP
}

extern "C" void kernel_launch(void* const* d_in, const int* in_sizes, int n_in,
                              void* d_out, int out_size, void* d_ws, size_t ws_size,
                              hipStream_t stream) {
    const float* x  = (const float*)d_in[0];
    // d_in[1] = t, unused by the reference computation
    const float* ff = (const float*)d_in[2];
    const float* fq = (const float*)d_in[3];
    float* out = (float*)d_out;
    hp_kernel<<<NBLOCKS, CPB, 0, stream>>>(x, ff, fq, out);
}